// Round 11
// baseline (182.399 us; speedup 1.0000x reference)
//
#include <hip/hip_runtime.h>
#include <math.h>

#define B_ 2
#define T_ 8
#define N_ 2048
#define F_ 64
#define TI 32                 // i-rows per block: two 16-row A-tiles share B-frags
#define JC 64
#define JCP 72
#define LOG2E 1.44269504088896f
#define PART_STRIDE ((size_t)B_ * T_ * N_ * F_)   // elements per partial buffer

typedef __attribute__((ext_vector_type(8))) short short8;
typedef __attribute__((ext_vector_type(4))) float f32x4;

__device__ __forceinline__ unsigned short f2bf(float x) {
  unsigned u = __float_as_uint(x);
  u += 0x7FFFu + ((u >> 16) & 1u);
  return (unsigned short)(u >> 16);
}

__device__ __forceinline__ unsigned cvt_pk_bf16(float lo, float hi) {
  unsigned r;
  asm("v_cvt_pk_bf16_f32 %0, %1, %2" : "=v"(r) : "v"(lo), "v"(hi));
  return r;
}

__device__ __forceinline__ float bf2f(unsigned short u) {
  return __uint_as_float(((unsigned)u) << 16);
}

// ---------------- prep: Wh = h@W (fp32), WhT bf16 [bt][f][j], Wh1/Wh2 (pre-scaled by log2e)
__global__ __launch_bounds__(256) void prep_kernel(
    const float* __restrict__ h, const float* __restrict__ W,
    const float* __restrict__ a, unsigned short* __restrict__ WhT,
    float* __restrict__ Wh1, float* __restrict__ Wh2) {
  __shared__ float Ws[64][64];
  __shared__ float hs[64][64];
  __shared__ float Whs[64][65];
  const int tid = threadIdx.x;
  const int row0 = blockIdx.x * 64;   // row in flattened [B*T*N]
  const int bt = row0 >> 11;
  const int j0 = row0 & 2047;
  // float4 staging: 4 vec-loads per thread instead of 16 scalar
  for (int i = tid; i < 1024; i += 256)
    ((f32x4*)Ws)[i] = ((const f32x4*)W)[i];
  for (int i = tid; i < 1024; i += 256)
    ((f32x4*)hs)[i] = ((const f32x4*)(h + (size_t)row0 * 64))[i];
  __syncthreads();
  const int f = tid & 63;
  const int rq = tid >> 6;
  float acc[16];
#pragma unroll
  for (int m = 0; m < 16; ++m) acc[m] = 0.f;
#pragma unroll 4
  for (int k = 0; k < 64; ++k) {
    const float wvv = Ws[k][f];
#pragma unroll
    for (int m = 0; m < 16; ++m) acc[m] = fmaf(hs[rq * 16 + m][k], wvv, acc[m]);
  }
#pragma unroll
  for (int m = 0; m < 16; ++m) Whs[rq * 16 + m][f] = acc[m];
  __syncthreads();
  {
    const int r = tid >> 2, q = tid & 3;
    float s1 = 0.f, s2 = 0.f;
#pragma unroll
    for (int k = 0; k < 16; ++k) {
      const float v = Whs[r][q * 16 + k];
      s1 = fmaf(v, a[q * 16 + k], s1);
      s2 = fmaf(v, a[64 + q * 16 + k], s2);
    }
    s1 += __shfl_xor(s1, 1); s1 += __shfl_xor(s1, 2);
    s2 += __shfl_xor(s2, 1); s2 += __shfl_xor(s2, 2);
    if (q == 0) {
      // pre-scale by log2(e): LeakyReLU is positively homogeneous, so
      // exp(LRelu(w1+w2)) == exp2(LRelu(log2e*w1 + log2e*w2))
      Wh1[(size_t)bt * N_ + j0 + r] = s1 * LOG2E;
      Wh2[(size_t)bt * N_ + j0 + r] = s2 * LOG2E;
    }
  }
  {
    const int ff = tid & 63, cp = tid >> 6;
#pragma unroll
    for (int cc = 0; cc < 2; ++cc) {
      const int c = cp * 2 + cc;
      short8 v;
#pragma unroll
      for (int k = 0; k < 8; ++k) v[k] = (short)f2bf(Whs[c * 8 + k][ff]);
      *(short8*)(WhT + ((size_t)bt * 64 + ff) * N_ + j0 + c * 8) = v;
    }
  }
}

// ---------------- main: softmax-over-T attention + MFMA PV -> bf16 partials
// Single-buffered atts (40960 B LDS total = exactly 4 blocks/CU, 32 waves/CU).
// Softmax exp-work happens in REGISTERS before barrier A (overlaps other
// blocks' MFMA); only the atts LDS write sits between barriers A and B.
__global__ __launch_bounds__(512, 8) void gat_mfma(
    const unsigned short* __restrict__ WhT, const float* __restrict__ Wh1,
    const float* __restrict__ Wh2, const int* __restrict__ adj,
    unsigned short* __restrict__ parts, const int njq) {
  __shared__ unsigned short atts[T_][TI][JCP];     // 36864 B (single buffer)
  __shared__ float wh2s[2][T_][JC];                // 4096 B -> 40960 total
  const int tid = threadIdx.x;
  const int jq = blockIdx.x % njq;
  const int rest = blockIdx.x / njq;
  const int i0 = (rest & 63) * TI;
  const int b = rest >> 6;
  const int jspan = N_ / njq;
  const int jbase = jq * jspan;
  const int nchunk = jspan / JC;

  const int wv = tid >> 6;        // wave id == t
  const int lane = tid & 63;
  const int col = lane & 15;
  const int kg = lane >> 4;

  const int sii = tid >> 4;          // softmax i-row 0..31
  const int sjj = (tid & 15) * 4;    // softmax j-cols sjj..sjj+3
  const int st = tid >> 6, sj = tid & 63;  // wh2 staging assignment

  const unsigned short* wtb = WhT + (size_t)(b * T_ + wv) * F_ * N_;
  const float* wh2b = Wh2 + (size_t)b * T_ * N_;
  const int* adjrow = adj + (size_t)(i0 + sii) * N_ + jbase;

  // Wh1 for this thread's softmax i-row (L2 broadcast loads, once per kernel)
  float w1r[T_];
#pragma unroll
  for (int t = 0; t < T_; ++t) w1r[t] = Wh1[(size_t)(b * T_ + t) * N_ + i0 + sii];

  f32x4 acc[2][4];
#pragma unroll
  for (int it = 0; it < 2; ++it)
#pragma unroll
    for (int nt = 0; nt < 4; ++nt) acc[it][nt] = {0.f, 0.f, 0.f, 0.f};

  // prologue: stage wh2 chunk 0, prefetch adj chunk 0
  wh2s[0][st][sj] = wh2b[(size_t)st * N_ + jbase + sj];
  int4 ad = *(const int4*)(adjrow + sjj);
  __syncthreads();

  for (int c = 0; c < nchunk; ++c) {
    const int j0 = jbase + c * JC;
    const int buf = c & 1;
    // --- issue B-fragment global loads early (shared by both A-tiles)
    short8 breg[4][2];
#pragma unroll
    for (int nt = 0; nt < 4; ++nt)
#pragma unroll
      for (int ks = 0; ks < 2; ++ks)
        breg[nt][ks] = *(const short8*)(wtb + (size_t)(nt * 16 + col) * N_ +
                                        j0 + ks * 32 + kg * 8);
    // --- stage next chunk's Wh2 into the other buffer
    if (c + 1 < nchunk)
      wh2s[buf ^ 1][st][sj] = wh2b[(size_t)st * N_ + j0 + JC + sj];
    // --- prefetch next chunk's adj
    int4 adn = ad;
    if (c + 1 < nchunk) adn = *(const int4*)(adjrow + (c + 1) * JC + sjj);

    // --- softmax over T in REGISTERS: row sii, 4 cols sjj..sjj+3
    unsigned pk[T_][2];
    {
      float e[T_][4];
      f32x4 s = {0.f, 0.f, 0.f, 0.f};
#pragma unroll
      for (int t = 0; t < T_; ++t) {
        const f32x4 q = *(const f32x4*)(&wh2s[buf][t][sjj]);
#pragma unroll
        for (int cc = 0; cc < 4; ++cc) {
          float x = w1r[t] + q[cc];
          x = fmaxf(x, 0.2f * x);   // LeakyReLU (alpha<1, scale-commuting)
          e[t][cc] = __builtin_amdgcn_exp2f(x);
          s[cc] += e[t][cc];
        }
      }
      // adj==0 -> all-NEG_INF column -> softmax over t uniform 1/8
      const int adc[4] = {ad.x, ad.y, ad.z, ad.w};
      float rr[4], dd[4];
#pragma unroll
      for (int cc = 0; cc < 4; ++cc) {
        rr[cc] = adc[cc] > 0 ? __builtin_amdgcn_rcpf(s[cc]) : 0.f;
        dd[cc] = adc[cc] > 0 ? 0.f : 0.125f;
      }
#pragma unroll
      for (int t = 0; t < T_; ++t) {
        pk[t][0] = cvt_pk_bf16(fmaf(e[t][0], rr[0], dd[0]),
                               fmaf(e[t][1], rr[1], dd[1]));
        pk[t][1] = cvt_pk_bf16(fmaf(e[t][2], rr[2], dd[2]),
                               fmaf(e[t][3], rr[3], dd[3]));
      }
    }
    ad = adn;
    __syncthreads();   // A: all waves' MFMA(c-1) finished reading atts
    // --- write atts (8 x ds_write_b64 per thread)
#pragma unroll
    for (int t = 0; t < T_; ++t)
      *(uint2*)&atts[t][sii][sjj] = make_uint2(pk[t][0], pk[t][1]);
    __syncthreads();   // B: atts ready
    // --- MFMA: two A-tiles (rows 0-15, 16-31) x 4 f-tiles, reusing breg
#pragma unroll
    for (int it = 0; it < 2; ++it) {
      const unsigned short* ab = &atts[wv][it * 16 + col][kg * 8];
      const short8 a0 = *(const short8*)ab;
      const short8 a1 = *(const short8*)(ab + 32);
#pragma unroll
      for (int nt = 0; nt < 4; ++nt) {
        acc[it][nt] = __builtin_amdgcn_mfma_f32_16x16x32_bf16(a0, breg[nt][0], acc[it][nt], 0, 0, 0);
        acc[it][nt] = __builtin_amdgcn_mfma_f32_16x16x32_bf16(a1, breg[nt][1], acc[it][nt], 0, 0, 0);
      }
    }
  }

  // ---- epilogue: bf16 partial store (1 cvt inst/elem). C/D: col=lane&15,
  // row=(lane>>4)*4+reg. Each jq owns a disjoint buffer -> no false sharing.
  unsigned short* ob = parts + (size_t)jq * PART_STRIDE +
                       ((size_t)(b * T_ + wv) * N_ + i0) * F_;
#pragma unroll
  for (int it = 0; it < 2; ++it) {
#pragma unroll
    for (int nt = 0; nt < 4; ++nt) {
#pragma unroll
      for (int r = 0; r < 4; ++r) {
        const int row = it * 16 + kg * 4 + r;
        const float x = acc[it][nt][r];
        ob[(size_t)row * F_ + nt * 16 + col] = (unsigned short)cvt_pk_bf16(x, x);
      }
    }
  }
}

// ---------------- combine njq bf16 partials + ELU -> fp32 out (16 elems/thread)
__global__ __launch_bounds__(256) void combine_elu(
    float* __restrict__ out, const unsigned short* __restrict__ parts,
    const int njq) {
  const size_t i = ((size_t)blockIdx.x * 256 + threadIdx.x) * 16;
  float s[16];
#pragma unroll
  for (int k = 0; k < 16; ++k) s[k] = 0.f;
  for (int p = 0; p < njq; ++p) {
    const unsigned short* pp = parts + (size_t)p * PART_STRIDE + i;
    const short8 v0 = *(const short8*)(pp);
    const short8 v1 = *(const short8*)(pp + 8);
#pragma unroll
    for (int k = 0; k < 8; ++k) {
      s[k]     += bf2f((unsigned short)v0[k]);
      s[8 + k] += bf2f((unsigned short)v1[k]);
    }
  }
#pragma unroll
  for (int q = 0; q < 4; ++q) {
    f32x4 r;
#pragma unroll
    for (int k = 0; k < 4; ++k) {
      const float x = s[q * 4 + k];
      r[k] = x > 0.f ? x : expm1f(x);
    }
    *(f32x4*)(out + i + q * 4) = r;
  }
}

extern "C" void kernel_launch(void* const* d_in, const int* in_sizes, int n_in,
                              void* d_out, int out_size, void* d_ws, size_t ws_size,
                              hipStream_t stream) {
  const float* h   = (const float*)d_in[0];
  const float* W   = (const float*)d_in[1];
  const float* a   = (const float*)d_in[2];
  const int*   adj = (const int*)d_in[3];
  float* out = (float*)d_out;

  const size_t whtBytes = (size_t)B_ * T_ * F_ * N_ * 2;    // 4MB
  const size_t vBytes   = (size_t)B_ * T_ * N_ * 4;         // 128KB
  const size_t partB    = PART_STRIDE * 2;                  // 4.2MB each (bf16)

  unsigned short* WhT = (unsigned short*)d_ws;
  float* Wh1 = (float*)((char*)d_ws + whtBytes);
  float* Wh2 = Wh1 + (size_t)B_ * T_ * N_;
  unsigned short* parts = (unsigned short*)(Wh2 + (size_t)B_ * T_ * N_);

  const size_t fixed = whtBytes + 2 * vBytes;
  const int njq = (ws_size >= fixed + 8 * partB) ? 8
                : (ws_size >= fixed + 4 * partB) ? 4
                : (ws_size >= fixed + 2 * partB) ? 2 : 1;

  hipLaunchKernelGGL(prep_kernel, dim3(B_ * T_ * N_ / 64), dim3(256), 0, stream,
                     h, W, a, WhT, Wh1, Wh2);
  hipLaunchKernelGGL(gat_mfma, dim3(B_ * (N_ / TI) * njq), dim3(512), 0, stream,
                     WhT, Wh1, Wh2, adj, parts, njq);
  hipLaunchKernelGGL(combine_elu, dim3((unsigned)(PART_STRIDE / (256 * 16))), dim3(256),
                     0, stream, out, parts, njq);
}

// Round 12
// 92.224 us; speedup vs baseline: 1.9778x; 1.9778x over previous
//
#include <hip/hip_runtime.h>
#include <math.h>

#define B_ 2
#define T_ 8
#define N_ 2048
#define F_ 64
#define TI 32                 // i-rows per block: two 16-row A-tiles share B-frags
#define JC 64
#define LOG2E 1.44269504088896f
#define PART_STRIDE ((size_t)B_ * T_ * N_ * F_)   // elements per partial buffer

typedef __attribute__((ext_vector_type(8))) short short8;
typedef __attribute__((ext_vector_type(4))) float f32x4;

__device__ __forceinline__ unsigned short f2bf(float x) {
  unsigned u = __float_as_uint(x);
  u += 0x7FFFu + ((u >> 16) & 1u);
  return (unsigned short)(u >> 16);
}

__device__ __forceinline__ unsigned cvt_pk_bf16(float lo, float hi) {
  unsigned r;
  asm("v_cvt_pk_bf16_f32 %0, %1, %2" : "=v"(r) : "v"(lo), "v"(hi));
  return r;
}

__device__ __forceinline__ float bf2f(unsigned short u) {
  return __uint_as_float(((unsigned)u) << 16);
}
__device__ __forceinline__ float bf_lo(unsigned u) { return __uint_as_float(u << 16); }
__device__ __forceinline__ float bf_hi(unsigned u) { return __uint_as_float(u & 0xFFFF0000u); }

// ---------------- prep: Wh = h@W (fp32), WhT bf16 [bt][f][j], Wh1/Wh2 (pre-scaled by log2e)
__global__ __launch_bounds__(256) void prep_kernel(
    const float* __restrict__ h, const float* __restrict__ W,
    const float* __restrict__ a, unsigned short* __restrict__ WhT,
    float* __restrict__ Wh1, float* __restrict__ Wh2) {
  __shared__ float Ws[64][64];
  __shared__ float hs[64][64];
  __shared__ float Whs[64][65];
  const int tid = threadIdx.x;
  const int row0 = blockIdx.x * 64;   // row in flattened [B*T*N]
  const int bt = row0 >> 11;
  const int j0 = row0 & 2047;
  for (int i = tid; i < 1024; i += 256)
    ((f32x4*)Ws)[i] = ((const f32x4*)W)[i];
  for (int i = tid; i < 1024; i += 256)
    ((f32x4*)hs)[i] = ((const f32x4*)(h + (size_t)row0 * 64))[i];
  __syncthreads();
  const int f = tid & 63;
  const int rq = tid >> 6;
  float acc[16];
#pragma unroll
  for (int m = 0; m < 16; ++m) acc[m] = 0.f;
#pragma unroll 4
  for (int k = 0; k < 64; ++k) {
    const float wvv = Ws[k][f];
#pragma unroll
    for (int m = 0; m < 16; ++m) acc[m] = fmaf(hs[rq * 16 + m][k], wvv, acc[m]);
  }
#pragma unroll
  for (int m = 0; m < 16; ++m) Whs[rq * 16 + m][f] = acc[m];
  __syncthreads();
  {
    const int r = tid >> 2, q = tid & 3;
    float s1 = 0.f, s2 = 0.f;
#pragma unroll
    for (int k = 0; k < 16; ++k) {
      const float v = Whs[r][q * 16 + k];
      s1 = fmaf(v, a[q * 16 + k], s1);
      s2 = fmaf(v, a[64 + q * 16 + k], s2);
    }
    s1 += __shfl_xor(s1, 1); s1 += __shfl_xor(s1, 2);
    s2 += __shfl_xor(s2, 1); s2 += __shfl_xor(s2, 2);
    if (q == 0) {
      // pre-scale by log2(e): LeakyReLU is positively homogeneous, so
      // exp(LRelu(w1+w2)) == exp2(LRelu(log2e*w1 + log2e*w2))
      Wh1[(size_t)bt * N_ + j0 + r] = s1 * LOG2E;
      Wh2[(size_t)bt * N_ + j0 + r] = s2 * LOG2E;
    }
  }
  {
    const int ff = tid & 63, cp = tid >> 6;
#pragma unroll
    for (int cc = 0; cc < 2; ++cc) {
      const int c = cp * 2 + cc;
      short8 v;
#pragma unroll
      for (int k = 0; k < 8; ++k) v[k] = (short)f2bf(Whs[c * 8 + k][ff]);
      *(short8*)(WhT + ((size_t)bt * 64 + ff) * N_ + j0 + c * 8) = v;
    }
  }
}

// ---------------- dmask: Rm[b][i][j/2] = packed bf16 pair of
// R = adj>0 ? 1/sum_t exp2(LRelu(w1[t][i]+w2[t][j])) : 0   (0 <=> masked)
__global__ __launch_bounds__(512) void dmask_kernel(
    const float* __restrict__ Wh1, const float* __restrict__ Wh2,
    const int* __restrict__ adj, unsigned* __restrict__ Rm) {
  const int tid = threadIdx.x;
  const int b = blockIdx.x >> 8;           // 256 blocks per batch
  const int i0 = (blockIdx.x & 255) * 8;
  const int si = tid >> 6;                 // i-row 0..7
  const int sj4 = (tid & 63) * 4;          // 4 j's per thread per iter
  const int irow = i0 + si;

  float w1r[T_];
#pragma unroll
  for (int t = 0; t < T_; ++t) w1r[t] = Wh1[(size_t)(b * T_ + t) * N_ + irow];

  const int* adjrow = adj + (size_t)irow * N_;
  unsigned* rmrow = Rm + ((size_t)b * N_ + irow) * (N_ / 2);
  const float* w2b = Wh2 + (size_t)b * T_ * N_;

  for (int it8 = 0; it8 < N_ / 256; ++it8) {
    const int j = it8 * 256 + sj4;
    const int4 ad = *(const int4*)(adjrow + j);
    f32x4 s = {0.f, 0.f, 0.f, 0.f};
#pragma unroll
    for (int t = 0; t < T_; ++t) {
      const f32x4 w2v = *(const f32x4*)(w2b + (size_t)t * N_ + j);
#pragma unroll
      for (int cc = 0; cc < 4; ++cc) {
        float x = w1r[t] + w2v[cc];
        x = fmaxf(x, 0.2f * x);   // LeakyReLU
        s[cc] += __builtin_amdgcn_exp2f(x);
      }
    }
    const float R0 = ad.x > 0 ? __builtin_amdgcn_rcpf(s[0]) : 0.f;
    const float R1 = ad.y > 0 ? __builtin_amdgcn_rcpf(s[1]) : 0.f;
    const float R2 = ad.z > 0 ? __builtin_amdgcn_rcpf(s[2]) : 0.f;
    const float R3 = ad.w > 0 ? __builtin_amdgcn_rcpf(s[3]) : 0.f;
    uint2 o;
    o.x = cvt_pk_bf16(R0, R1);
    o.y = cvt_pk_bf16(R2, R3);
    *(uint2*)(rmrow + (j >> 1)) = o;
  }
}

// ---------------- main: BARRIER-FREE, LDS-FREE. Each wave (t = wave id)
// recomputes its own numerators e_t in-lane and builds the MFMA A-fragment
// in registers: att = (R!=0) ? e*R : 1/8. No cross-wave communication.
__global__ __launch_bounds__(512, 4) void gat_mfma(
    const unsigned short* __restrict__ WhT, const float* __restrict__ Wh1,
    const float* __restrict__ Wh2, const unsigned* __restrict__ Rm,
    unsigned short* __restrict__ parts, const int njq) {
  const int tid = threadIdx.x;
  const int jq = blockIdx.x % njq;
  const int rest = blockIdx.x / njq;
  const int i0 = (rest & 63) * TI;
  const int b = rest >> 6;
  const int jspan = N_ / njq;
  const int jbase = jq * jspan;
  const int nchunk = jspan / JC;

  const int wv = tid >> 6;        // wave id == t
  const int lane = tid & 63;
  const int col = lane & 15;
  const int kg = lane >> 4;

  const unsigned short* wtb = WhT + (size_t)(b * T_ + wv) * F_ * N_;
  const float* w2row = Wh2 + (size_t)(b * T_ + wv) * N_;
  const float w1r0 = Wh1[(size_t)(b * T_ + wv) * N_ + i0 + col];
  const float w1r1 = Wh1[(size_t)(b * T_ + wv) * N_ + i0 + 16 + col];
  const unsigned* rmb0 = Rm + ((size_t)b * N_ + i0 + col) * (N_ / 2);
  const unsigned* rmb1 = Rm + ((size_t)b * N_ + i0 + 16 + col) * (N_ / 2);

  f32x4 acc[2][4];
#pragma unroll
  for (int it = 0; it < 2; ++it)
#pragma unroll
    for (int nt = 0; nt < 4; ++nt) acc[it][nt] = {0.f, 0.f, 0.f, 0.f};

  for (int c = 0; c < nchunk; ++c) {
    const int j0 = jbase + c * JC;
    // --- B-fragments (WhT)
    short8 breg[4][2];
#pragma unroll
    for (int nt = 0; nt < 4; ++nt)
#pragma unroll
      for (int ks = 0; ks < 2; ++ks)
        breg[nt][ks] = *(const short8*)(wtb + (size_t)(nt * 16 + col) * N_ +
                                        j0 + ks * 32 + kg * 8);
    // --- packed reciprocal-denominators: [it][ks] -> 8 j's = uint4
    uint4 rm[2][2];
    rm[0][0] = *(const uint4*)(rmb0 + ((j0 + kg * 8) >> 1));
    rm[0][1] = *(const uint4*)(rmb0 + ((j0 + 32 + kg * 8) >> 1));
    rm[1][0] = *(const uint4*)(rmb1 + ((j0 + kg * 8) >> 1));
    rm[1][1] = *(const uint4*)(rmb1 + ((j0 + 32 + kg * 8) >> 1));
    // --- Wh2 segment for this wave's t: [ks][q]
    f32x4 w2v[2][2];
#pragma unroll
    for (int ks = 0; ks < 2; ++ks)
#pragma unroll
      for (int q = 0; q < 2; ++q)
        w2v[ks][q] = *(const f32x4*)(w2row + j0 + ks * 32 + kg * 8 + q * 4);

    // --- A-fragments in registers: att = R!=0 ? exp2(LRelu(w1+w2))*R : 1/8
    short8 af[2][2];
#pragma unroll
    for (int it = 0; it < 2; ++it) {
      const float w1v = it == 0 ? w1r0 : w1r1;
#pragma unroll
      for (int ks = 0; ks < 2; ++ks) {
        float att[8];
#pragma unroll
        for (int k = 0; k < 8; ++k) {
          float x = w1v + w2v[ks][k >> 2][k & 3];
          x = fmaxf(x, 0.2f * x);
          const float e = __builtin_amdgcn_exp2f(x);
          const unsigned m = ((const unsigned*)&rm[it][ks])[k >> 1];
          const float Rf = (k & 1) ? bf_hi(m) : bf_lo(m);
          att[k] = Rf != 0.f ? e * Rf : 0.125f;
        }
        unsigned au[4];
#pragma unroll
        for (int p = 0; p < 4; ++p) au[p] = cvt_pk_bf16(att[2 * p], att[2 * p + 1]);
        af[it][ks] = *(short8*)au;
      }
    }
    // --- MFMA
#pragma unroll
    for (int nt = 0; nt < 4; ++nt) {
      acc[0][nt] = __builtin_amdgcn_mfma_f32_16x16x32_bf16(af[0][0], breg[nt][0], acc[0][nt], 0, 0, 0);
      acc[0][nt] = __builtin_amdgcn_mfma_f32_16x16x32_bf16(af[0][1], breg[nt][1], acc[0][nt], 0, 0, 0);
      acc[1][nt] = __builtin_amdgcn_mfma_f32_16x16x32_bf16(af[1][0], breg[nt][0], acc[1][nt], 0, 0, 0);
      acc[1][nt] = __builtin_amdgcn_mfma_f32_16x16x32_bf16(af[1][1], breg[nt][1], acc[1][nt], 0, 0, 0);
    }
  }

  // ---- epilogue: bf16 partial store. C/D: col=lane&15, row=(lane>>4)*4+reg
  unsigned short* ob = parts + (size_t)jq * PART_STRIDE +
                       ((size_t)(b * T_ + wv) * N_ + i0) * F_;
#pragma unroll
  for (int it = 0; it < 2; ++it) {
#pragma unroll
    for (int nt = 0; nt < 4; ++nt) {
#pragma unroll
      for (int r = 0; r < 4; ++r) {
        const int row = it * 16 + kg * 4 + r;
        const float x = acc[it][nt][r];
        ob[(size_t)row * F_ + nt * 16 + col] = (unsigned short)cvt_pk_bf16(x, x);
      }
    }
  }
}

// ---------------- combine njq bf16 partials + ELU -> fp32 out (16 elems/thread)
__global__ __launch_bounds__(256) void combine_elu(
    float* __restrict__ out, const unsigned short* __restrict__ parts,
    const int njq) {
  const size_t i = ((size_t)blockIdx.x * 256 + threadIdx.x) * 16;
  float s[16];
#pragma unroll
  for (int k = 0; k < 16; ++k) s[k] = 0.f;
  for (int p = 0; p < njq; ++p) {
    const unsigned short* pp = parts + (size_t)p * PART_STRIDE + i;
    const short8 v0 = *(const short8*)(pp);
    const short8 v1 = *(const short8*)(pp + 8);
#pragma unroll
    for (int k = 0; k < 8; ++k) {
      s[k]     += bf2f((unsigned short)v0[k]);
      s[8 + k] += bf2f((unsigned short)v1[k]);
    }
  }
#pragma unroll
  for (int q = 0; q < 4; ++q) {
    f32x4 r;
#pragma unroll
    for (int k = 0; k < 4; ++k) {
      const float x = s[q * 4 + k];
      r[k] = x > 0.f ? x : expm1f(x);
    }
    *(f32x4*)(out + i + q * 4) = r;
  }
}

extern "C" void kernel_launch(void* const* d_in, const int* in_sizes, int n_in,
                              void* d_out, int out_size, void* d_ws, size_t ws_size,
                              hipStream_t stream) {
  const float* h   = (const float*)d_in[0];
  const float* W   = (const float*)d_in[1];
  const float* a   = (const float*)d_in[2];
  const int*   adj = (const int*)d_in[3];
  float* out = (float*)d_out;

  const size_t whtBytes = (size_t)B_ * T_ * F_ * N_ * 2;    // 4MB
  const size_t vBytes   = (size_t)B_ * T_ * N_ * 4;         // 128KB
  const size_t rmBytes  = (size_t)B_ * N_ * (N_ / 2) * 4;   // 16.8MB
  const size_t partB    = PART_STRIDE * 2;                  // 4.2MB each (bf16)

  unsigned short* WhT = (unsigned short*)d_ws;
  float* Wh1 = (float*)((char*)d_ws + whtBytes);
  float* Wh2 = Wh1 + (size_t)B_ * T_ * N_;
  unsigned* Rm = (unsigned*)((char*)d_ws + whtBytes + 2 * vBytes);
  unsigned short* parts = (unsigned short*)((char*)Rm + rmBytes);

  const size_t fixed = whtBytes + 2 * vBytes + rmBytes;
  const int njq = (ws_size >= fixed + 4 * partB) ? 4
                : (ws_size >= fixed + 2 * partB) ? 2 : 1;

  hipLaunchKernelGGL(prep_kernel, dim3(B_ * T_ * N_ / 64), dim3(256), 0, stream,
                     h, W, a, WhT, Wh1, Wh2);
  hipLaunchKernelGGL(dmask_kernel, dim3(B_ * (N_ / 8)), dim3(512), 0, stream,
                     Wh1, Wh2, adj, Rm);
  hipLaunchKernelGGL(gat_mfma, dim3(B_ * (N_ / TI) * njq), dim3(512), 0, stream,
                     WhT, Wh1, Wh2, Rm, parts, njq);
  hipLaunchKernelGGL(combine_elu, dim3((unsigned)(PART_STRIDE / (256 * 16))), dim3(256),
                     0, stream, out, parts, njq);
}

// Round 13
// 54.941 us; speedup vs baseline: 3.3199x; 1.6786x over previous
//
#include <hip/hip_runtime.h>
#include <math.h>

#define B_ 2
#define T_ 8
#define N_ 2048
#define F_ 64
#define TI 64                 // i-rows per block; waves = (t)x(f-half)
#define JC 64
#define JCP 72
#define LOG2E 1.44269504088896f
#define PART_STRIDE ((size_t)B_ * T_ * N_ * F_)   // elements per partial buffer

typedef __attribute__((ext_vector_type(8))) short short8;
typedef __attribute__((ext_vector_type(4))) float f32x4;

__device__ __forceinline__ unsigned short f2bf(float x) {
  unsigned u = __float_as_uint(x);
  u += 0x7FFFu + ((u >> 16) & 1u);
  return (unsigned short)(u >> 16);
}

__device__ __forceinline__ unsigned cvt_pk_bf16(float lo, float hi) {
  unsigned r;
  asm("v_cvt_pk_bf16_f32 %0, %1, %2" : "=v"(r) : "v"(lo), "v"(hi));
  return r;
}

__device__ __forceinline__ float bf2f(unsigned short u) {
  return __uint_as_float(((unsigned)u) << 16);
}

// ---------------- prep: Wh = h@W (fp32), WhT bf16 [bt][f][j], Wh1/Wh2 (pre-scaled by log2e)
__global__ __launch_bounds__(256) void prep_kernel(
    const float* __restrict__ h, const float* __restrict__ W,
    const float* __restrict__ a, unsigned short* __restrict__ WhT,
    float* __restrict__ Wh1, float* __restrict__ Wh2) {
  __shared__ float Ws[64][64];
  __shared__ float hs[64][64];
  __shared__ float Whs[64][65];
  const int tid = threadIdx.x;
  const int row0 = blockIdx.x * 64;   // row in flattened [B*T*N]
  const int bt = row0 >> 11;
  const int j0 = row0 & 2047;
  for (int i = tid; i < 1024; i += 256)
    ((f32x4*)Ws)[i] = ((const f32x4*)W)[i];
  for (int i = tid; i < 1024; i += 256)
    ((f32x4*)hs)[i] = ((const f32x4*)(h + (size_t)row0 * 64))[i];
  __syncthreads();
  const int f = tid & 63;
  const int rq = tid >> 6;
  float acc[16];
#pragma unroll
  for (int m = 0; m < 16; ++m) acc[m] = 0.f;
#pragma unroll 4
  for (int k = 0; k < 64; ++k) {
    const float wvv = Ws[k][f];
#pragma unroll
    for (int m = 0; m < 16; ++m) acc[m] = fmaf(hs[rq * 16 + m][k], wvv, acc[m]);
  }
#pragma unroll
  for (int m = 0; m < 16; ++m) Whs[rq * 16 + m][f] = acc[m];
  __syncthreads();
  {
    const int r = tid >> 2, q = tid & 3;
    float s1 = 0.f, s2 = 0.f;
#pragma unroll
    for (int k = 0; k < 16; ++k) {
      const float v = Whs[r][q * 16 + k];
      s1 = fmaf(v, a[q * 16 + k], s1);
      s2 = fmaf(v, a[64 + q * 16 + k], s2);
    }
    s1 += __shfl_xor(s1, 1); s1 += __shfl_xor(s1, 2);
    s2 += __shfl_xor(s2, 1); s2 += __shfl_xor(s2, 2);
    if (q == 0) {
      // pre-scale by log2(e): LeakyReLU is positively homogeneous, so
      // exp(LRelu(w1+w2)) == exp2(LRelu(log2e*w1 + log2e*w2))
      Wh1[(size_t)bt * N_ + j0 + r] = s1 * LOG2E;
      Wh2[(size_t)bt * N_ + j0 + r] = s2 * LOG2E;
    }
  }
  {
    const int ff = tid & 63, cp = tid >> 6;
#pragma unroll
    for (int cc = 0; cc < 2; ++cc) {
      const int c = cp * 2 + cc;
      short8 v;
#pragma unroll
      for (int k = 0; k < 8; ++k) v[k] = (short)f2bf(Whs[c * 8 + k][ff]);
      *(short8*)(WhT + ((size_t)bt * 64 + ff) * N_ + j0 + c * 8) = v;
    }
  }
}

// ---------------- main: softmax-over-T attention + MFMA PV -> bf16 partials
// TI=64, 1024 threads, 16 waves = (t 0..7) x (f-half 0..1). Each wave computes
// 4 A-tiles x 2 f-tiles from ONE set of B-fragments -> B-frag L2 traffic halves
// vs TI=32 (128MB total). Single-buffered atts, 2 barriers/chunk.
__global__ __launch_bounds__(1024, 4) void gat_mfma(
    const unsigned short* __restrict__ WhT, const float* __restrict__ Wh1,
    const float* __restrict__ Wh2, const int* __restrict__ adj,
    unsigned short* __restrict__ parts, const int njq) {
  __shared__ unsigned short atts[T_][TI][JCP];     // 73728 B (single buffer)
  __shared__ float wh2s[2][T_][JC];                // 4096 B -> 77824 total
  const int tid = threadIdx.x;
  const int jq = blockIdx.x % njq;
  const int rest = blockIdx.x / njq;
  const int i0 = (rest & 31) * TI;
  const int b = rest >> 5;
  const int jspan = N_ / njq;
  const int jbase = jq * jspan;
  const int nchunk = jspan / JC;

  const int wv = tid >> 6;        // wave id 0..15
  const int t = wv & 7;           // MFMA wave's T index
  const int fh = wv >> 3;         // f-half 0..1
  const int lane = tid & 63;
  const int col = lane & 15;
  const int kg = lane >> 4;

  const int sii = tid >> 4;          // softmax i-row 0..63
  const int sjj = (tid & 15) * 4;    // softmax j-cols sjj..sjj+3

  const unsigned short* wtb = WhT + (size_t)(b * T_ + t) * F_ * N_;
  const float* wh2b = Wh2 + (size_t)b * T_ * N_;
  const int* adjrow = adj + (size_t)(i0 + sii) * N_ + jbase;

  // Wh1 for this thread's softmax i-row (L2 broadcast loads, once per kernel)
  float w1r[T_];
#pragma unroll
  for (int tt = 0; tt < T_; ++tt)
    w1r[tt] = Wh1[(size_t)(b * T_ + tt) * N_ + i0 + sii];

  f32x4 acc[4][2];
#pragma unroll
  for (int it = 0; it < 4; ++it)
#pragma unroll
    for (int nt = 0; nt < 2; ++nt) acc[it][nt] = {0.f, 0.f, 0.f, 0.f};

  // prologue: stage wh2 chunk 0 (512 threads suffice), prefetch adj chunk 0
  if (tid < 512) wh2s[0][tid >> 6][tid & 63] = wh2b[(size_t)(tid >> 6) * N_ + jbase + (tid & 63)];
  int4 ad = *(const int4*)(adjrow + sjj);
  __syncthreads();

  for (int c = 0; c < nchunk; ++c) {
    const int j0 = jbase + c * JC;
    const int buf = c & 1;
    // --- B-fragment global loads (2 f-tiles for this wave's f-half)
    short8 breg[2][2];
#pragma unroll
    for (int nt = 0; nt < 2; ++nt)
#pragma unroll
      for (int ks = 0; ks < 2; ++ks)
        breg[nt][ks] = *(const short8*)(wtb + (size_t)(fh * 32 + nt * 16 + col) * N_ +
                                        j0 + ks * 32 + kg * 8);
    // --- stage next chunk's Wh2 into the other buffer
    if (c + 1 < nchunk && tid < 512)
      wh2s[buf ^ 1][tid >> 6][tid & 63] = wh2b[(size_t)(tid >> 6) * N_ + j0 + JC + (tid & 63)];
    // --- prefetch next chunk's adj
    int4 adn = ad;
    if (c + 1 < nchunk) adn = *(const int4*)(adjrow + (c + 1) * JC + sjj);

    // --- softmax over T in registers: row sii, cols sjj..sjj+3
    unsigned pk[T_][2];
    {
      float e[T_][4];
      f32x4 s = {0.f, 0.f, 0.f, 0.f};
#pragma unroll
      for (int tt = 0; tt < T_; ++tt) {
        const f32x4 q = *(const f32x4*)(&wh2s[buf][tt][sjj]);
#pragma unroll
        for (int cc = 0; cc < 4; ++cc) {
          float x = w1r[tt] + q[cc];
          x = fmaxf(x, 0.2f * x);   // LeakyReLU (alpha<1, scale-commuting)
          e[tt][cc] = __builtin_amdgcn_exp2f(x);
          s[cc] += e[tt][cc];
        }
      }
      // adj==0 -> all-NEG_INF column -> softmax over t uniform 1/8
      const int adc[4] = {ad.x, ad.y, ad.z, ad.w};
      float rr[4], dd[4];
#pragma unroll
      for (int cc = 0; cc < 4; ++cc) {
        rr[cc] = adc[cc] > 0 ? __builtin_amdgcn_rcpf(s[cc]) : 0.f;
        dd[cc] = adc[cc] > 0 ? 0.f : 0.125f;
      }
#pragma unroll
      for (int tt = 0; tt < T_; ++tt) {
        pk[tt][0] = cvt_pk_bf16(fmaf(e[tt][0], rr[0], dd[0]),
                                fmaf(e[tt][1], rr[1], dd[1]));
        pk[tt][1] = cvt_pk_bf16(fmaf(e[tt][2], rr[2], dd[2]),
                                fmaf(e[tt][3], rr[3], dd[3]));
      }
    }
    ad = adn;
    __syncthreads();   // A: all waves' MFMA(c-1) finished reading atts
#pragma unroll
    for (int tt = 0; tt < T_; ++tt)
      *(uint2*)&atts[tt][sii][sjj] = make_uint2(pk[tt][0], pk[tt][1]);
    __syncthreads();   // B: atts(c) ready
    // --- MFMA: 4 A-tiles (rows 0..63) x 2 f-tiles, reusing breg
#pragma unroll
    for (int it = 0; it < 4; ++it) {
      const unsigned short* ab = &atts[t][it * 16 + col][kg * 8];
      const short8 a0 = *(const short8*)ab;
      const short8 a1 = *(const short8*)(ab + 32);
#pragma unroll
      for (int nt = 0; nt < 2; ++nt) {
        acc[it][nt] = __builtin_amdgcn_mfma_f32_16x16x32_bf16(a0, breg[nt][0], acc[it][nt], 0, 0, 0);
        acc[it][nt] = __builtin_amdgcn_mfma_f32_16x16x32_bf16(a1, breg[nt][1], acc[it][nt], 0, 0, 0);
      }
    }
  }

  // ---- epilogue: bf16 partial store. C/D: col=lane&15, row=(lane>>4)*4+reg
  unsigned short* ob = parts + (size_t)jq * PART_STRIDE +
                       ((size_t)(b * T_ + t) * N_ + i0) * F_;
#pragma unroll
  for (int it = 0; it < 4; ++it) {
#pragma unroll
    for (int nt = 0; nt < 2; ++nt) {
#pragma unroll
      for (int r = 0; r < 4; ++r) {
        const int row = it * 16 + kg * 4 + r;
        const float x = acc[it][nt][r];
        ob[(size_t)row * F_ + fh * 32 + nt * 16 + col] = (unsigned short)cvt_pk_bf16(x, x);
      }
    }
  }
}

// ---------------- combine njq bf16 partials + ELU -> fp32 out (16 elems/thread)
__global__ __launch_bounds__(256) void combine_elu(
    float* __restrict__ out, const unsigned short* __restrict__ parts,
    const int njq) {
  const size_t i = ((size_t)blockIdx.x * 256 + threadIdx.x) * 16;
  float s[16];
#pragma unroll
  for (int k = 0; k < 16; ++k) s[k] = 0.f;
  for (int p = 0; p < njq; ++p) {
    const unsigned short* pp = parts + (size_t)p * PART_STRIDE + i;
    const short8 v0 = *(const short8*)(pp);
    const short8 v1 = *(const short8*)(pp + 8);
#pragma unroll
    for (int k = 0; k < 8; ++k) {
      s[k]     += bf2f((unsigned short)v0[k]);
      s[8 + k] += bf2f((unsigned short)v1[k]);
    }
  }
#pragma unroll
  for (int q = 0; q < 4; ++q) {
    f32x4 r;
#pragma unroll
    for (int k = 0; k < 4; ++k) {
      const float x = s[q * 4 + k];
      r[k] = x > 0.f ? x : expm1f(x);
    }
    *(f32x4*)(out + i + q * 4) = r;
  }
}

extern "C" void kernel_launch(void* const* d_in, const int* in_sizes, int n_in,
                              void* d_out, int out_size, void* d_ws, size_t ws_size,
                              hipStream_t stream) {
  const float* h   = (const float*)d_in[0];
  const float* W   = (const float*)d_in[1];
  const float* a   = (const float*)d_in[2];
  const int*   adj = (const int*)d_in[3];
  float* out = (float*)d_out;

  const size_t whtBytes = (size_t)B_ * T_ * F_ * N_ * 2;    // 4MB
  const size_t vBytes   = (size_t)B_ * T_ * N_ * 4;         // 128KB
  const size_t partB    = PART_STRIDE * 2;                  // 4.2MB each (bf16)

  unsigned short* WhT = (unsigned short*)d_ws;
  float* Wh1 = (float*)((char*)d_ws + whtBytes);
  float* Wh2 = Wh1 + (size_t)B_ * T_ * N_;
  unsigned short* parts = (unsigned short*)(Wh2 + (size_t)B_ * T_ * N_);

  const size_t fixed = whtBytes + 2 * vBytes;
  const int njq = (ws_size >= fixed + 4 * partB) ? 4
                : (ws_size >= fixed + 2 * partB) ? 2 : 1;

  hipLaunchKernelGGL(prep_kernel, dim3(B_ * T_ * N_ / 64), dim3(256), 0, stream,
                     h, W, a, WhT, Wh1, Wh2);
  hipLaunchKernelGGL(gat_mfma, dim3(B_ * (N_ / TI) * njq), dim3(1024), 0, stream,
                     WhT, Wh1, Wh2, adj, parts, njq);
  hipLaunchKernelGGL(combine_elu, dim3((unsigned)(PART_STRIDE / (256 * 16))), dim3(256),
                     0, stream, out, parts, njq);
}

// Round 14
// 53.949 us; speedup vs baseline: 3.3810x; 1.0184x over previous
//
#include <hip/hip_runtime.h>
#include <math.h>

#define B_ 2
#define T_ 8
#define N_ 2048
#define F_ 64
#define TI 64                 // i-rows per block; waves = (t)x(f-half)
#define JC 64
#define JCP 72
#define LOG2E 1.44269504088896f
#define PART_STRIDE ((size_t)B_ * T_ * N_ * F_)   // elements per partial buffer

typedef __attribute__((ext_vector_type(8))) short short8;
typedef __attribute__((ext_vector_type(4))) float f32x4;

__device__ __forceinline__ unsigned short f2bf(float x) {
  unsigned u = __float_as_uint(x);
  u += 0x7FFFu + ((u >> 16) & 1u);
  return (unsigned short)(u >> 16);
}

__device__ __forceinline__ unsigned cvt_pk_bf16(float lo, float hi) {
  unsigned r;
  asm("v_cvt_pk_bf16_f32 %0, %1, %2" : "=v"(r) : "v"(lo), "v"(hi));
  return r;
}

__device__ __forceinline__ float bf2f(unsigned short u) {
  return __uint_as_float(((unsigned)u) << 16);
}

// ---------------- prep: Wh = h@W (fp32), WhT bf16 [bt][f][j], Wh1/Wh2 (pre-scaled by log2e)
__global__ __launch_bounds__(256) void prep_kernel(
    const float* __restrict__ h, const float* __restrict__ W,
    const float* __restrict__ a, unsigned short* __restrict__ WhT,
    float* __restrict__ Wh1, float* __restrict__ Wh2) {
  __shared__ float Ws[64][64];
  __shared__ float hs[64][64];
  __shared__ float Whs[64][65];
  const int tid = threadIdx.x;
  const int row0 = blockIdx.x * 64;   // row in flattened [B*T*N]
  const int bt = row0 >> 11;
  const int j0 = row0 & 2047;
  for (int i = tid; i < 1024; i += 256)
    ((f32x4*)Ws)[i] = ((const f32x4*)W)[i];
  for (int i = tid; i < 1024; i += 256)
    ((f32x4*)hs)[i] = ((const f32x4*)(h + (size_t)row0 * 64))[i];
  __syncthreads();
  const int f = tid & 63;
  const int rq = tid >> 6;
  float acc[16];
#pragma unroll
  for (int m = 0; m < 16; ++m) acc[m] = 0.f;
#pragma unroll 4
  for (int k = 0; k < 64; ++k) {
    const float wvv = Ws[k][f];
#pragma unroll
    for (int m = 0; m < 16; ++m) acc[m] = fmaf(hs[rq * 16 + m][k], wvv, acc[m]);
  }
#pragma unroll
  for (int m = 0; m < 16; ++m) Whs[rq * 16 + m][f] = acc[m];
  __syncthreads();
  {
    const int r = tid >> 2, q = tid & 3;
    float s1 = 0.f, s2 = 0.f;
#pragma unroll
    for (int k = 0; k < 16; ++k) {
      const float v = Whs[r][q * 16 + k];
      s1 = fmaf(v, a[q * 16 + k], s1);
      s2 = fmaf(v, a[64 + q * 16 + k], s2);
    }
    s1 += __shfl_xor(s1, 1); s1 += __shfl_xor(s1, 2);
    s2 += __shfl_xor(s2, 1); s2 += __shfl_xor(s2, 2);
    if (q == 0) {
      // pre-scale by log2(e): LeakyReLU is positively homogeneous, so
      // exp(LRelu(w1+w2)) == exp2(LRelu(log2e*w1 + log2e*w2))
      Wh1[(size_t)bt * N_ + j0 + r] = s1 * LOG2E;
      Wh2[(size_t)bt * N_ + j0 + r] = s2 * LOG2E;
    }
  }
  {
    const int ff = tid & 63, cp = tid >> 6;
#pragma unroll
    for (int cc = 0; cc < 2; ++cc) {
      const int c = cp * 2 + cc;
      short8 v;
#pragma unroll
      for (int k = 0; k < 8; ++k) v[k] = (short)f2bf(Whs[c * 8 + k][ff]);
      *(short8*)(WhT + ((size_t)bt * 64 + ff) * N_ + j0 + c * 8) = v;
    }
  }
}

// ---------------- main: softmax-over-T attention + MFMA PV -> bf16 partials
// TI=64, 1024 threads, 16 waves = (t 0..7) x (f-half 0..1). B-frag traffic
// 128MB (TI=64). DOUBLE-buffered atts -> ONE barrier per chunk: write(c) is
// after barrier(c-1); any MFMA(c-2) on the same buffer is before it. MFMA(c)
// and softmax(c+1) share a barrier-free region (wave-level overlap).
__global__ __launch_bounds__(1024, 4) void gat_mfma(
    const unsigned short* __restrict__ WhT, const float* __restrict__ Wh1,
    const float* __restrict__ Wh2, const int* __restrict__ adj,
    unsigned short* __restrict__ parts, const int njq) {
  __shared__ unsigned short atts[2][T_][TI][JCP];  // 147456 B (double buffer)
  __shared__ float wh2s[2][T_][JC];                // 4096 B -> 151552 total
  const int tid = threadIdx.x;
  const int jq = blockIdx.x % njq;
  const int rest = blockIdx.x / njq;
  const int i0 = (rest & 31) * TI;
  const int b = rest >> 5;
  const int jspan = N_ / njq;
  const int jbase = jq * jspan;
  const int nchunk = jspan / JC;

  const int wv = tid >> 6;        // wave id 0..15
  const int t = wv & 7;           // MFMA wave's T index
  const int fh = wv >> 3;         // f-half 0..1
  const int lane = tid & 63;
  const int col = lane & 15;
  const int kg = lane >> 4;

  const int sii = tid >> 4;          // softmax i-row 0..63
  const int sjj = (tid & 15) * 4;    // softmax j-cols sjj..sjj+3

  const unsigned short* wtb = WhT + (size_t)(b * T_ + t) * F_ * N_;
  const float* wh2b = Wh2 + (size_t)b * T_ * N_;
  const int* adjrow = adj + (size_t)(i0 + sii) * N_ + jbase;

  // Wh1 for this thread's softmax i-row (L2 broadcast loads, once per kernel)
  float w1r[T_];
#pragma unroll
  for (int tt = 0; tt < T_; ++tt)
    w1r[tt] = Wh1[(size_t)(b * T_ + tt) * N_ + i0 + sii];

  f32x4 acc[4][2];
#pragma unroll
  for (int it = 0; it < 4; ++it)
#pragma unroll
    for (int nt = 0; nt < 2; ++nt) acc[it][nt] = {0.f, 0.f, 0.f, 0.f};

  // prologue: stage wh2 chunk 0 (512 threads suffice), prefetch adj chunk 0
  if (tid < 512) wh2s[0][tid >> 6][tid & 63] = wh2b[(size_t)(tid >> 6) * N_ + jbase + (tid & 63)];
  int4 ad = *(const int4*)(adjrow + sjj);
  __syncthreads();

  for (int c = 0; c < nchunk; ++c) {
    const int j0 = jbase + c * JC;
    const int buf = c & 1;
    // --- B-fragment global loads (2 f-tiles for this wave's f-half)
    short8 breg[2][2];
#pragma unroll
    for (int nt = 0; nt < 2; ++nt)
#pragma unroll
      for (int ks = 0; ks < 2; ++ks)
        breg[nt][ks] = *(const short8*)(wtb + (size_t)(fh * 32 + nt * 16 + col) * N_ +
                                        j0 + ks * 32 + kg * 8);
    // --- stage next chunk's Wh2 into the other buffer (reader of that buffer
    //     was softmax(c-1), which completed before barrier(c-1))
    if (c + 1 < nchunk && tid < 512)
      wh2s[buf ^ 1][tid >> 6][tid & 63] = wh2b[(size_t)(tid >> 6) * N_ + j0 + JC + (tid & 63)];
    // --- prefetch next chunk's adj
    int4 adn = ad;
    if (c + 1 < nchunk) adn = *(const int4*)(adjrow + (c + 1) * JC + sjj);

    // --- softmax over T in registers: row sii, cols sjj..sjj+3
    unsigned pk[T_][2];
    {
      float e[T_][4];
      f32x4 s = {0.f, 0.f, 0.f, 0.f};
#pragma unroll
      for (int tt = 0; tt < T_; ++tt) {
        const f32x4 q = *(const f32x4*)(&wh2s[buf][tt][sjj]);
#pragma unroll
        for (int cc = 0; cc < 4; ++cc) {
          float x = w1r[tt] + q[cc];
          x = fmaxf(x, 0.2f * x);   // LeakyReLU (alpha<1, scale-commuting)
          e[tt][cc] = __builtin_amdgcn_exp2f(x);
          s[cc] += e[tt][cc];
        }
      }
      // adj==0 -> all-NEG_INF column -> softmax over t uniform 1/8
      const int adc[4] = {ad.x, ad.y, ad.z, ad.w};
      float rr[4], dd[4];
#pragma unroll
      for (int cc = 0; cc < 4; ++cc) {
        rr[cc] = adc[cc] > 0 ? __builtin_amdgcn_rcpf(s[cc]) : 0.f;
        dd[cc] = adc[cc] > 0 ? 0.f : 0.125f;
      }
#pragma unroll
      for (int tt = 0; tt < T_; ++tt) {
        pk[tt][0] = cvt_pk_bf16(fmaf(e[tt][0], rr[0], dd[0]),
                                fmaf(e[tt][1], rr[1], dd[1]));
        pk[tt][1] = cvt_pk_bf16(fmaf(e[tt][2], rr[2], dd[2]),
                                fmaf(e[tt][3], rr[3], dd[3]));
      }
    }
    ad = adn;
    // --- write atts[buf] (dbuf: no pre-write barrier needed)
#pragma unroll
    for (int tt = 0; tt < T_; ++tt)
      *(uint2*)&atts[buf][tt][sii][sjj] = make_uint2(pk[tt][0], pk[tt][1]);
    __syncthreads();   // atts[buf](c) ready; MFMA(c-1) on buf^1 already passed
    // --- MFMA: 4 A-tiles (rows 0..63) x 2 f-tiles, reusing breg
#pragma unroll
    for (int it = 0; it < 4; ++it) {
      const unsigned short* ab = &atts[buf][t][it * 16 + col][kg * 8];
      const short8 a0 = *(const short8*)ab;
      const short8 a1 = *(const short8*)(ab + 32);
#pragma unroll
      for (int nt = 0; nt < 2; ++nt) {
        acc[it][nt] = __builtin_amdgcn_mfma_f32_16x16x32_bf16(a0, breg[nt][0], acc[it][nt], 0, 0, 0);
        acc[it][nt] = __builtin_amdgcn_mfma_f32_16x16x32_bf16(a1, breg[nt][1], acc[it][nt], 0, 0, 0);
      }
    }
  }

  // ---- epilogue: bf16 partial store. C/D: col=lane&15, row=(lane>>4)*4+reg
  unsigned short* ob = parts + (size_t)jq * PART_STRIDE +
                       ((size_t)(b * T_ + t) * N_ + i0) * F_;
#pragma unroll
  for (int it = 0; it < 4; ++it) {
#pragma unroll
    for (int nt = 0; nt < 2; ++nt) {
#pragma unroll
      for (int r = 0; r < 4; ++r) {
        const int row = it * 16 + kg * 4 + r;
        const float x = acc[it][nt][r];
        ob[(size_t)row * F_ + fh * 32 + nt * 16 + col] = (unsigned short)cvt_pk_bf16(x, x);
      }
    }
  }
}

// ---------------- combine njq bf16 partials + ELU -> fp32 out (16 elems/thread)
__global__ __launch_bounds__(256) void combine_elu(
    float* __restrict__ out, const unsigned short* __restrict__ parts,
    const int njq) {
  const size_t i = ((size_t)blockIdx.x * 256 + threadIdx.x) * 16;
  float s[16];
#pragma unroll
  for (int k = 0; k < 16; ++k) s[k] = 0.f;
  for (int p = 0; p < njq; ++p) {
    const unsigned short* pp = parts + (size_t)p * PART_STRIDE + i;
    const short8 v0 = *(const short8*)(pp);
    const short8 v1 = *(const short8*)(pp + 8);
#pragma unroll
    for (int k = 0; k < 8; ++k) {
      s[k]     += bf2f((unsigned short)v0[k]);
      s[8 + k] += bf2f((unsigned short)v1[k]);
    }
  }
#pragma unroll
  for (int q = 0; q < 4; ++q) {
    f32x4 r;
#pragma unroll
    for (int k = 0; k < 4; ++k) {
      const float x = s[q * 4 + k];
      r[k] = x > 0.f ? x : expm1f(x);
    }
    *(f32x4*)(out + i + q * 4) = r;
  }
}

extern "C" void kernel_launch(void* const* d_in, const int* in_sizes, int n_in,
                              void* d_out, int out_size, void* d_ws, size_t ws_size,
                              hipStream_t stream) {
  const float* h   = (const float*)d_in[0];
  const float* W   = (const float*)d_in[1];
  const float* a   = (const float*)d_in[2];
  const int*   adj = (const int*)d_in[3];
  float* out = (float*)d_out;

  const size_t whtBytes = (size_t)B_ * T_ * F_ * N_ * 2;    // 4MB
  const size_t vBytes   = (size_t)B_ * T_ * N_ * 4;         // 128KB
  const size_t partB    = PART_STRIDE * 2;                  // 4.2MB each (bf16)

  unsigned short* WhT = (unsigned short*)d_ws;
  float* Wh1 = (float*)((char*)d_ws + whtBytes);
  float* Wh2 = Wh1 + (size_t)B_ * T_ * N_;
  unsigned short* parts = (unsigned short*)(Wh2 + (size_t)B_ * T_ * N_);

  const size_t fixed = whtBytes + 2 * vBytes;
  const int njq = (ws_size >= fixed + 4 * partB) ? 4
                : (ws_size >= fixed + 2 * partB) ? 2 : 1;

  hipLaunchKernelGGL(prep_kernel, dim3(B_ * T_ * N_ / 64), dim3(256), 0, stream,
                     h, W, a, WhT, Wh1, Wh2);
  hipLaunchKernelGGL(gat_mfma, dim3(B_ * (N_ / TI) * njq), dim3(1024), 0, stream,
                     WhT, Wh1, Wh2, adj, parts, njq);
  hipLaunchKernelGGL(combine_elu, dim3((unsigned)(PART_STRIDE / (256 * 16))), dim3(256),
                     0, stream, out, parts, njq);
}

// Round 15
// 52.236 us; speedup vs baseline: 3.4918x; 1.0328x over previous
//
#include <hip/hip_runtime.h>
#include <math.h>

#define B_ 2
#define T_ 8
#define N_ 2048
#define F_ 64
#define TI 64                 // i-rows per block; waves = (t)x(f-half)
#define JC 64
#define JCP 72
#define LOG2E 1.44269504088896f
#define PART_STRIDE ((size_t)B_ * T_ * N_ * F_)   // elements per partial buffer

typedef __attribute__((ext_vector_type(8))) short short8;
typedef __attribute__((ext_vector_type(4))) float f32x4;

__device__ __forceinline__ unsigned short f2bf(float x) {
  unsigned u = __float_as_uint(x);
  u += 0x7FFFu + ((u >> 16) & 1u);
  return (unsigned short)(u >> 16);
}

__device__ __forceinline__ unsigned cvt_pk_bf16(float lo, float hi) {
  unsigned r;
  asm("v_cvt_pk_bf16_f32 %0, %1, %2" : "=v"(r) : "v"(lo), "v"(hi));
  return r;
}

__device__ __forceinline__ float bf2f(unsigned short u) {
  return __uint_as_float(((unsigned)u) << 16);
}

// ---------------- prep: Wh = h@W (fp32), WhT bf16 [bt][f][j],
// U1/V1/U2/V2 rank-1 factor tables: exp2(LRelu(w1+w2)) == max(U1*U2, V1*V2)
__global__ __launch_bounds__(256) void prep_kernel(
    const float* __restrict__ h, const float* __restrict__ W,
    const float* __restrict__ a, unsigned short* __restrict__ WhT,
    float* __restrict__ U1, float* __restrict__ V1,
    float* __restrict__ U2, float* __restrict__ V2) {
  __shared__ float Ws[64][64];
  __shared__ float hs[64][64];
  __shared__ float Whs[64][65];
  const int tid = threadIdx.x;
  const int row0 = blockIdx.x * 64;   // row in flattened [B*T*N]
  const int bt = row0 >> 11;
  const int j0 = row0 & 2047;
  for (int i = tid; i < 1024; i += 256)
    ((f32x4*)Ws)[i] = ((const f32x4*)W)[i];
  for (int i = tid; i < 1024; i += 256)
    ((f32x4*)hs)[i] = ((const f32x4*)(h + (size_t)row0 * 64))[i];
  __syncthreads();
  const int f = tid & 63;
  const int rq = tid >> 6;
  float acc[16];
#pragma unroll
  for (int m = 0; m < 16; ++m) acc[m] = 0.f;
#pragma unroll 4
  for (int k = 0; k < 64; ++k) {
    const float wvv = Ws[k][f];
#pragma unroll
    for (int m = 0; m < 16; ++m) acc[m] = fmaf(hs[rq * 16 + m][k], wvv, acc[m]);
  }
#pragma unroll
  for (int m = 0; m < 16; ++m) Whs[rq * 16 + m][f] = acc[m];
  __syncthreads();
  {
    const int r = tid >> 2, q = tid & 3;
    float s1 = 0.f, s2 = 0.f;
#pragma unroll
    for (int k = 0; k < 16; ++k) {
      const float v = Whs[r][q * 16 + k];
      s1 = fmaf(v, a[q * 16 + k], s1);
      s2 = fmaf(v, a[64 + q * 16 + k], s2);
    }
    s1 += __shfl_xor(s1, 1); s1 += __shfl_xor(s1, 2);
    s2 += __shfl_xor(s2, 1); s2 += __shfl_xor(s2, 2);
    if (q == 0) {
      // exp(LRelu(s1+s2)) = exp2(LRelu(log2e*s1 + log2e*s2))
      //                   = max(exp2(z1)*exp2(z2), exp2(.2z1)*exp2(.2z2))
      const float z1 = s1 * LOG2E, z2 = s2 * LOG2E;
      const size_t idx = (size_t)bt * N_ + j0 + r;
      U1[idx] = __builtin_amdgcn_exp2f(z1);
      V1[idx] = __builtin_amdgcn_exp2f(0.2f * z1);
      U2[idx] = __builtin_amdgcn_exp2f(z2);
      V2[idx] = __builtin_amdgcn_exp2f(0.2f * z2);
    }
  }
  {
    const int ff = tid & 63, cp = tid >> 6;
#pragma unroll
    for (int cc = 0; cc < 2; ++cc) {
      const int c = cp * 2 + cc;
      short8 v;
#pragma unroll
      for (int k = 0; k < 8; ++k) v[k] = (short)f2bf(Whs[c * 8 + k][ff]);
      *(short8*)(WhT + ((size_t)bt * 64 + ff) * N_ + j0 + c * 8) = v;
    }
  }
}

// ---------------- main: softmax-over-T attention + MFMA PV -> bf16 partials
// TI=64, 1024 threads, 16 waves = (t 0..7) x (f-half 0..1). Double-buffered
// atts, ONE barrier per chunk. Numerators via rank-1 factors (NO exp in-loop):
// e[t] = max(u1[t,i]*u2[t,j], v1[t,i]*v2[t,j]).
__global__ __launch_bounds__(1024, 4) void gat_mfma(
    const unsigned short* __restrict__ WhT,
    const float* __restrict__ U1, const float* __restrict__ V1,
    const float* __restrict__ U2, const float* __restrict__ V2,
    const int* __restrict__ adj,
    unsigned short* __restrict__ parts, const int njq) {
  __shared__ unsigned short atts[2][T_][TI][JCP];  // 147456 B (double buffer)
  __shared__ float uv2s[2][2][T_][JC];             // 8192 B -> 155648 total
  const int tid = threadIdx.x;
  const int jq = blockIdx.x % njq;
  const int rest = blockIdx.x / njq;
  const int i0 = (rest & 31) * TI;
  const int b = rest >> 5;
  const int jspan = N_ / njq;
  const int jbase = jq * jspan;
  const int nchunk = jspan / JC;

  const int wv = tid >> 6;        // wave id 0..15
  const int t = wv & 7;           // MFMA wave's T index
  const int fh = wv >> 3;         // f-half 0..1
  const int lane = tid & 63;
  const int col = lane & 15;
  const int kg = lane >> 4;

  const int sii = tid >> 4;          // softmax i-row 0..63
  const int sjj = (tid & 15) * 4;    // softmax j-cols sjj..sjj+3
  // uv2 staging assignment: tab = tid>>9, t = (tid>>6)&7, j = tid&63
  const int stab = tid >> 9, stt = (tid >> 6) & 7, sjn = tid & 63;

  const unsigned short* wtb = WhT + (size_t)(b * T_ + t) * F_ * N_;
  const float* uvsrc = (stab ? V2 : U2) + (size_t)(b * T_ + stt) * N_;
  const int* adjrow = adj + (size_t)(i0 + sii) * N_ + jbase;

  // rank-1 i-side factors for this thread's softmax row (broadcast loads, once)
  float u1r[T_], v1r[T_];
#pragma unroll
  for (int tt = 0; tt < T_; ++tt) {
    u1r[tt] = U1[(size_t)(b * T_ + tt) * N_ + i0 + sii];
    v1r[tt] = V1[(size_t)(b * T_ + tt) * N_ + i0 + sii];
  }

  f32x4 acc[4][2];
#pragma unroll
  for (int it = 0; it < 4; ++it)
#pragma unroll
    for (int nt = 0; nt < 2; ++nt) acc[it][nt] = {0.f, 0.f, 0.f, 0.f};

  // prologue: stage uv2 chunk 0, prefetch adj chunk 0
  uv2s[0][stab][stt][sjn] = uvsrc[jbase + sjn];
  int4 ad = *(const int4*)(adjrow + sjj);
  __syncthreads();

  for (int c = 0; c < nchunk; ++c) {
    const int j0 = jbase + c * JC;
    const int buf = c & 1;
    // --- B-fragment global loads (2 f-tiles for this wave's f-half)
    short8 breg[2][2];
#pragma unroll
    for (int nt = 0; nt < 2; ++nt)
#pragma unroll
      for (int ks = 0; ks < 2; ++ks)
        breg[nt][ks] = *(const short8*)(wtb + (size_t)(fh * 32 + nt * 16 + col) * N_ +
                                        j0 + ks * 32 + kg * 8);
    // --- stage next chunk's u2/v2 into the other buffer
    if (c + 1 < nchunk)
      uv2s[buf ^ 1][stab][stt][sjn] = uvsrc[j0 + JC + sjn];
    // --- prefetch next chunk's adj
    int4 adn = ad;
    if (c + 1 < nchunk) adn = *(const int4*)(adjrow + (c + 1) * JC + sjj);

    // --- softmax over T, NO exponentials: e = max(u1*u2, v1*v2)
    unsigned pk[T_][2];
    {
      float e[T_][4];
      f32x4 s = {0.f, 0.f, 0.f, 0.f};
#pragma unroll
      for (int tt = 0; tt < T_; ++tt) {
        const f32x4 qu = *(const f32x4*)(&uv2s[buf][0][tt][sjj]);
        const f32x4 qv = *(const f32x4*)(&uv2s[buf][1][tt][sjj]);
#pragma unroll
        for (int cc = 0; cc < 4; ++cc) {
          const float x = fmaxf(u1r[tt] * qu[cc], v1r[tt] * qv[cc]);
          e[tt][cc] = x;
          s[cc] += x;
        }
      }
      // adj==0 -> all-NEG_INF column -> softmax over t uniform 1/8
      const int adc[4] = {ad.x, ad.y, ad.z, ad.w};
      float rr[4], dd[4];
#pragma unroll
      for (int cc = 0; cc < 4; ++cc) {
        rr[cc] = adc[cc] > 0 ? __builtin_amdgcn_rcpf(s[cc]) : 0.f;
        dd[cc] = adc[cc] > 0 ? 0.f : 0.125f;
      }
#pragma unroll
      for (int tt = 0; tt < T_; ++tt) {
        pk[tt][0] = cvt_pk_bf16(fmaf(e[tt][0], rr[0], dd[0]),
                                fmaf(e[tt][1], rr[1], dd[1]));
        pk[tt][1] = cvt_pk_bf16(fmaf(e[tt][2], rr[2], dd[2]),
                                fmaf(e[tt][3], rr[3], dd[3]));
      }
    }
    ad = adn;
    // --- write atts[buf] (dbuf: no pre-write barrier needed)
#pragma unroll
    for (int tt = 0; tt < T_; ++tt)
      *(uint2*)&atts[buf][tt][sii][sjj] = make_uint2(pk[tt][0], pk[tt][1]);
    __syncthreads();   // atts[buf](c) ready; MFMA(c-1) on buf^1 already passed
    // --- MFMA: 4 A-tiles (rows 0..63) x 2 f-tiles, reusing breg
#pragma unroll
    for (int it = 0; it < 4; ++it) {
      const unsigned short* ab = &atts[buf][t][it * 16 + col][kg * 8];
      const short8 a0 = *(const short8*)ab;
      const short8 a1 = *(const short8*)(ab + 32);
#pragma unroll
      for (int nt = 0; nt < 2; ++nt) {
        acc[it][nt] = __builtin_amdgcn_mfma_f32_16x16x32_bf16(a0, breg[nt][0], acc[it][nt], 0, 0, 0);
        acc[it][nt] = __builtin_amdgcn_mfma_f32_16x16x32_bf16(a1, breg[nt][1], acc[it][nt], 0, 0, 0);
      }
    }
  }

  // ---- epilogue: bf16 partial store. C/D: col=lane&15, row=(lane>>4)*4+reg
  unsigned short* ob = parts + (size_t)jq * PART_STRIDE +
                       ((size_t)(b * T_ + t) * N_ + i0) * F_;
#pragma unroll
  for (int it = 0; it < 4; ++it) {
#pragma unroll
    for (int nt = 0; nt < 2; ++nt) {
#pragma unroll
      for (int r = 0; r < 4; ++r) {
        const int row = it * 16 + kg * 4 + r;
        const float x = acc[it][nt][r];
        ob[(size_t)row * F_ + fh * 32 + nt * 16 + col] = (unsigned short)cvt_pk_bf16(x, x);
      }
    }
  }
}

// ---------------- combine njq bf16 partials + ELU -> fp32 out (16 elems/thread)
__global__ __launch_bounds__(256) void combine_elu(
    float* __restrict__ out, const unsigned short* __restrict__ parts,
    const int njq) {
  const size_t i = ((size_t)blockIdx.x * 256 + threadIdx.x) * 16;
  float s[16];
#pragma unroll
  for (int k = 0; k < 16; ++k) s[k] = 0.f;
  for (int p = 0; p < njq; ++p) {
    const unsigned short* pp = parts + (size_t)p * PART_STRIDE + i;
    const short8 v0 = *(const short8*)(pp);
    const short8 v1 = *(const short8*)(pp + 8);
#pragma unroll
    for (int k = 0; k < 8; ++k) {
      s[k]     += bf2f((unsigned short)v0[k]);
      s[8 + k] += bf2f((unsigned short)v1[k]);
    }
  }
#pragma unroll
  for (int q = 0; q < 4; ++q) {
    f32x4 r;
#pragma unroll
    for (int k = 0; k < 4; ++k) {
      const float x = s[q * 4 + k];
      r[k] = x > 0.f ? x : expm1f(x);
    }
    *(f32x4*)(out + i + q * 4) = r;
  }
}

extern "C" void kernel_launch(void* const* d_in, const int* in_sizes, int n_in,
                              void* d_out, int out_size, void* d_ws, size_t ws_size,
                              hipStream_t stream) {
  const float* h   = (const float*)d_in[0];
  const float* W   = (const float*)d_in[1];
  const float* a   = (const float*)d_in[2];
  const int*   adj = (const int*)d_in[3];
  float* out = (float*)d_out;

  const size_t whtBytes = (size_t)B_ * T_ * F_ * N_ * 2;    // 4MB
  const size_t vBytes   = (size_t)B_ * T_ * N_ * 4;         // 128KB each
  const size_t partB    = PART_STRIDE * 2;                  // 4.2MB each (bf16)

  unsigned short* WhT = (unsigned short*)d_ws;
  float* U1 = (float*)((char*)d_ws + whtBytes);
  float* V1 = U1 + (size_t)B_ * T_ * N_;
  float* U2 = V1 + (size_t)B_ * T_ * N_;
  float* V2 = U2 + (size_t)B_ * T_ * N_;
  unsigned short* parts = (unsigned short*)(V2 + (size_t)B_ * T_ * N_);

  const size_t fixed = whtBytes + 4 * vBytes;
  const int njq = (ws_size >= fixed + 4 * partB) ? 4
                : (ws_size >= fixed + 2 * partB) ? 2 : 1;

  hipLaunchKernelGGL(prep_kernel, dim3(B_ * T_ * N_ / 64), dim3(256), 0, stream,
                     h, W, a, WhT, U1, V1, U2, V2);
  hipLaunchKernelGGL(gat_mfma, dim3(B_ * (N_ / TI) * njq), dim3(1024), 0, stream,
                     WhT, U1, V1, U2, V2, adj, parts, njq);
  hipLaunchKernelGGL(combine_elu, dim3((unsigned)(PART_STRIDE / (256 * 16))), dim3(256),
                     0, stream, out, parts, njq);
}